// Round 2
// baseline (525.202 us; speedup 1.0000x reference)
//
#include <hip/hip_runtime.h>
#include <hip/hip_fp16.h>

// Rotation_9242769622431 — round 5: compose-then-GEMM.
// Round-4 post-mortem: conflicts fixed (7.2e7->1.3e7) but kernel is now
// VALU-bound (54% VALUBusy) on scalar Givens math — 128 iters x (readlane+fma)
// per thread. The 8 layers + scale are a fixed 128x128 matrix per group:
// Out[:,G_g] = X[:,G_g] * M_g. So: compose M_g once (tiny kernel reusing the
// verified round-4 rotation loop on an identity tile), then do 32 block-diagonal
// GEMMs with mfma_f32_16x16x32_{f16,bf16}. HBM floor ~42us vs 177us now.
// Fragment layouts per m89/m97: A lane: row=l%16, k=8*(l>>4)+i (contiguous 8);
// B lane: col=l%16, same k; D: col=l&15, row=(l>>4)*4+reg. LDS staged with
// XOR chunk swizzle (c ^= r&7 in 16B units) -> 2-way = free on frag reads.
// Safety: fp32 in-kernel fallback; round-4 kernel retained if ws < 1MiB.

typedef unsigned int uint32;
typedef unsigned short ushort;

#define DIM    4096
#define GROUP  128
#define KROT   8
#define NGROUP 32
#define TPAD   (GROUP + 1)

typedef float    f32x4 __attribute__((ext_vector_type(4)));
typedef _Float16 f16x8 __attribute__((ext_vector_type(8)));
typedef short    s16x8 __attribute__((ext_vector_type(8)));

__device__ __forceinline__ float bf16_to_f(ushort u) {
    union { uint32 i; float f; } v; v.i = ((uint32)u) << 16; return v.f;
}
__device__ __forceinline__ ushort f_to_bf16(float f) {
    union { float f; uint32 i; } v; v.f = f;
    uint32 x = v.i;
    return (ushort)((x + 0x7fffu + ((x >> 16) & 1u)) >> 16);  // RNE
}
__device__ __forceinline__ float fp16_to_f(ushort u) {
    __half h = __ushort_as_half(u); return __half2float(h);
}
__device__ __forceinline__ ushort f_to_fp16(float f) {
    return __half_as_ushort(__float2half_rn(f));
}
__device__ __forceinline__ float bcast_f(float x, int lane) {
    return __uint_as_float(__builtin_amdgcn_readlane(__float_as_uint(x), lane));
}

// flag: 0 = fp32, 1 = bf16, 2 = fp16
__global__ __launch_bounds__(256) void detect_dtype(const uint32* __restrict__ scw,
                                                    int* __restrict__ flag) {
    __shared__ int cbf[256], cfp16[256];
    int b = 0, h = 0;
    for (int i = threadIdx.x; i < 2048; i += 256) {
        uint32 lo = scw[i] & 0xffffu;
        b += (lo >= 0x3F00u && lo <= 0x3FC0u);        // bf16 in [0.5, 1.5]
        h += (lo >= 0x3800u && lo <= 0x3E00u);        // fp16 in [0.5, 1.5]
    }
    cbf[threadIdx.x] = b; cfp16[threadIdx.x] = h;
    __syncthreads();
    for (int s = 128; s > 0; s >>= 1) {
        if (threadIdx.x < s) { cbf[threadIdx.x] += cbf[threadIdx.x + s];
                               cfp16[threadIdx.x] += cfp16[threadIdx.x + s]; }
        __syncthreads();
    }
    if (threadIdx.x == 0)
        *flag = (cbf[0] > 1024) ? 1 : ((cfp16[0] > 1024) ? 2 : 0);
}

// ---------------------------------------------------------------------------
// compose_M: 64 blocks = 32 groups x 2 row-halves. Builds M_g = A_0..A_7*diag(s)
// by applying the (verified) column-rotation loop to a 64-row identity slab,
// then stores TRANSPOSED (Mt[j][i], j = out col, i = in row) in dtype halves.
// ---------------------------------------------------------------------------
__global__ __launch_bounds__(256) void compose_M(
    const int*  __restrict__ pairs,
    const void* __restrict__ thetav,
    const void* __restrict__ scalesv,
    ushort*     __restrict__ Mt,
    const int*  __restrict__ flagp)
{
    __shared__ float tile[64][TPAD];
    const int dt = *flagp;
    if (dt == 0) return;                       // fp32 path needs no M
    const int g    = blockIdx.x >> 1;
    const int half = blockIdx.x & 1;
    const int r0   = half * 64;
    const int tid  = threadIdx.x;
    const int l    = tid & 63;
    const int w    = tid >> 6;
    const int pmine = w * 16 + (l & 15);

    int A[KROT], B[KROT]; float C[KROT], S[KROT];
    #pragma unroll
    for (int k = 0; k < KROT; ++k) {
        A[k] = pairs[k * DIM + g * GROUP + 2 * pmine];
        B[k] = pairs[k * DIM + g * GROUP + 2 * pmine + 1];
        int ti = k * (DIM / 2) + g * (GROUP / 2) + pmine;
        float th = (dt == 1) ? bf16_to_f(((const ushort*)thetav)[ti])
                             : fp16_to_f(((const ushort*)thetav)[ti]);
        float c = __builtin_cosf(th), s = __builtin_sinf(th);
        // match reference quantization: c,s cast to x.dtype before use
        if (dt == 1) { c = bf16_to_f(f_to_bf16(c)); s = bf16_to_f(f_to_bf16(s)); }
        else         { c = fp16_to_f(f_to_fp16(c)); s = fp16_to_f(f_to_fp16(s)); }
        C[k] = c; S[k] = s;
    }

    for (int idx = tid; idx < 64 * GROUP; idx += 256) {
        int r = idx >> 7, c = idx & 127;
        tile[r][c] = (r0 + r == c) ? 1.0f : 0.0f;
    }
    __syncthreads();

    #pragma unroll
    for (int k = 0; k < KROT; ++k) {
        #pragma unroll
        for (int pp = 0; pp < 16; ++pp) {
            int   a = __builtin_amdgcn_readlane(A[k], pp);
            int   b = __builtin_amdgcn_readlane(B[k], pp);
            float c = bcast_f(C[k], pp);
            float s = bcast_f(S[k], pp);
            float xa = tile[l][a], xb = tile[l][b];
            tile[l][a] = c * xa - s * xb;
            tile[l][b] = s * xa + c * xb;
        }
        __syncthreads();
    }

    // transposed store: Mt[g][j][i], this block covers i in [r0, r0+64)
    for (int it = 0; it < 4; ++it) {
        int idx = it * 256 + tid;                 // 128 j x 8 chunks
        int j = idx >> 3, cc = idx & 7;
        float sj = (dt == 1) ? bf16_to_f(((const ushort*)scalesv)[g * GROUP + j])
                             : fp16_to_f(((const ushort*)scalesv)[g * GROUP + j]);
        uint32 ws4[4];
        #pragma unroll
        for (int h2 = 0; h2 < 4; ++h2) {
            float lo = tile[cc * 8 + 2 * h2][j]     * sj;
            float hi = tile[cc * 8 + 2 * h2 + 1][j] * sj;
            ushort ulo = (dt == 1) ? f_to_bf16(lo) : f_to_fp16(lo);
            ushort uhi = (dt == 1) ? f_to_bf16(hi) : f_to_fp16(hi);
            ws4[h2] = (uint32)ulo | ((uint32)uhi << 16);
        }
        uint4 v; v.x = ws4[0]; v.y = ws4[1]; v.z = ws4[2]; v.w = ws4[3];
        *(uint4*)(Mt + (size_t)g * GROUP * GROUP + (size_t)j * GROUP
                     + ((size_t)(half * 8 + cc)) * 8) = v;
    }
}

// ---------------------------------------------------------------------------
// rotate_gemm: block = (64-row tile, group). Out = Xtile(64x128) * Mt^T.
// 4 waves in 2x2: wave (wr,wc) owns rows [wr*32,+32) x cols [wc*64,+64).
// ---------------------------------------------------------------------------
template <int DT>
__device__ __forceinline__ void gemm_core(const ushort* __restrict__ xs,
                                          const ushort* __restrict__ mt,
                                          f32x4 acc[2][4], int l, int wr, int wc)
{
    const int lr = l & 15, q = l >> 4;
    union U { uint4 u; f16x8 h; s16x8 s; };
    #pragma unroll
    for (int kk = 0; kk < 4; ++kk) {
        U av[2];
        #pragma unroll
        for (int mf = 0; mf < 2; ++mf) {
            int r = wr * 32 + mf * 16 + lr;
            int c = (kk * 4 + q) ^ (r & 7);
            av[mf].u = *(const uint4*)(xs + (size_t)r * GROUP + (size_t)c * 8);
        }
        #pragma unroll
        for (int nf = 0; nf < 4; ++nf) {
            int n = wc * 64 + nf * 16 + lr;
            int c = (kk * 4 + q) ^ (n & 7);
            U bv; bv.u = *(const uint4*)(mt + (size_t)n * GROUP + (size_t)c * 8);
            #pragma unroll
            for (int mf = 0; mf < 2; ++mf) {
                if constexpr (DT == 2)
                    acc[mf][nf] = __builtin_amdgcn_mfma_f32_16x16x32_f16(
                        av[mf].h, bv.h, acc[mf][nf], 0, 0, 0);
                else
                    acc[mf][nf] = __builtin_amdgcn_mfma_f32_16x16x32_bf16(
                        av[mf].s, bv.s, acc[mf][nf], 0, 0, 0);
            }
        }
    }
}

__global__ __launch_bounds__(256) void rotate_gemm(
    const void* __restrict__ Xv,
    const ushort* __restrict__ Mt,
    void* __restrict__ Outv,
    const int* __restrict__ flagp,
    const int* __restrict__ pairs,
    const void* __restrict__ thetav,
    const void* __restrict__ scalesv)
{
    __shared__ union __align__(16) {
        struct { ushort xs[64 * GROUP]; ushort mt[GROUP * GROUP]; } s;  // 48 KB
        ushort os[64][136];                                             // 17.4 KB
        struct { float tile[64][TPAD]; float scl[GROUP]; } fb;          // 33.5 KB
    } sh;
    const int dt   = *flagp;
    const int row0 = blockIdx.x * 64;
    const int g    = blockIdx.y;
    const int tid  = threadIdx.x;
    const int l    = tid & 63;
    const int w    = tid >> 6;

    if (dt != 0) {
        // ---- stage X tile (coalesced global, XOR-swizzled LDS write) ----
        const uint4* X4 = (const uint4*)Xv;                 // 8 halves / uint4
        #pragma unroll
        for (int it = 0; it < 4; ++it) {
            int i = it * 256 + tid;
            int r = i >> 4, c = i & 15;
            uint4 v = X4[(size_t)(row0 + r) * (DIM / 8) + g * (GROUP / 8) + c];
            *(uint4*)(sh.s.xs + (size_t)r * GROUP + (size_t)(c ^ (r & 7)) * 8) = v;
        }
        // ---- stage Mt (L2-resident, 32 KB) ----
        const uint4* M4 = (const uint4*)(Mt + (size_t)g * GROUP * GROUP);
        #pragma unroll
        for (int it = 0; it < 8; ++it) {
            int i = it * 256 + tid;
            int n = i >> 4, c = i & 15;
            uint4 v = M4[i];
            *(uint4*)(sh.s.mt + (size_t)n * GROUP + (size_t)(c ^ (n & 7)) * 8) = v;
        }
        __syncthreads();

        const int wr = w >> 1, wc = w & 1;
        f32x4 acc[2][4];
        #pragma unroll
        for (int mf = 0; mf < 2; ++mf)
            #pragma unroll
            for (int nf = 0; nf < 4; ++nf)
                acc[mf][nf] = (f32x4)0.0f;

        if (dt == 2) gemm_core<2>(sh.s.xs, sh.s.mt, acc, l, wr, wc);
        else         gemm_core<1>(sh.s.xs, sh.s.mt, acc, l, wr, wc);
        __syncthreads();   // before overlaying xs/mt with os

        // ---- D frags -> LDS (D: col = l&15, row = (l>>4)*4 + j) ----
        const int lr = l & 15, q = l >> 4;
        #pragma unroll
        for (int mf = 0; mf < 2; ++mf) {
            #pragma unroll
            for (int nf = 0; nf < 4; ++nf) {
                int r  = wr * 32 + mf * 16 + q * 4;
                int cc = wc * 64 + nf * 16 + lr;
                #pragma unroll
                for (int j = 0; j < 4; ++j) {
                    float vv = acc[mf][nf][j];
                    sh.os[r + j][cc] = (dt == 1) ? f_to_bf16(vv) : f_to_fp16(vv);
                }
            }
        }
        __syncthreads();

        // ---- coalesced store ----
        uint4* O4 = (uint4*)Outv;
        #pragma unroll
        for (int it = 0; it < 2; ++it) {
            int i = it * 256 + tid;
            int r = i >> 3, c8 = i & 7;
            uint4 v = *(const uint4*)(&sh.os[r][c8 * 8]);
            O4[(size_t)(row0 + r) * (DIM / 8) + g * (GROUP / 8) + c8] = v;
        }
        return;
    }

    // ------------------- dt == 0: fp32 direct fallback -------------------
    const int pmine = w * 16 + (l & 15);
    if (tid < GROUP) sh.fb.scl[tid] = ((const float*)scalesv)[g * GROUP + tid];
    int A[KROT], B[KROT]; float C[KROT], S[KROT];
    #pragma unroll
    for (int k = 0; k < KROT; ++k) {
        A[k] = pairs[k * DIM + g * GROUP + 2 * pmine];
        B[k] = pairs[k * DIM + g * GROUP + 2 * pmine + 1];
        int ti = k * (DIM / 2) + g * (GROUP / 2) + pmine;
        float th = ((const float*)thetav)[ti];
        C[k] = __builtin_cosf(th); S[k] = __builtin_sinf(th);
    }
    const float4* Xf = (const float4*)Xv;
    for (int i = tid; i < 64 * 32; i += 256) {
        int r = i >> 5, c4 = i & 31;
        float4 v = Xf[(size_t)(row0 + r) * (DIM / 4) + g * (GROUP / 4) + c4];
        sh.fb.tile[r][c4 * 4 + 0] = v.x; sh.fb.tile[r][c4 * 4 + 1] = v.y;
        sh.fb.tile[r][c4 * 4 + 2] = v.z; sh.fb.tile[r][c4 * 4 + 3] = v.w;
    }
    __syncthreads();
    #pragma unroll
    for (int k = 0; k < KROT; ++k) {
        #pragma unroll
        for (int pp = 0; pp < 16; ++pp) {
            int   a = __builtin_amdgcn_readlane(A[k], pp);
            int   b = __builtin_amdgcn_readlane(B[k], pp);
            float c = bcast_f(C[k], pp);
            float s = bcast_f(S[k], pp);
            float xa = sh.fb.tile[l][a], xb = sh.fb.tile[l][b];
            sh.fb.tile[l][a] = c * xa - s * xb;
            sh.fb.tile[l][b] = s * xa + c * xb;
        }
        __syncthreads();
    }
    float4* Of = (float4*)Outv;
    for (int i = tid; i < 64 * 32; i += 256) {
        int r = i >> 5, c4 = i & 31;
        float4 v;
        v.x = sh.fb.tile[r][c4 * 4 + 0] * sh.fb.scl[c4 * 4 + 0];
        v.y = sh.fb.tile[r][c4 * 4 + 1] * sh.fb.scl[c4 * 4 + 1];
        v.z = sh.fb.tile[r][c4 * 4 + 2] * sh.fb.scl[c4 * 4 + 2];
        v.w = sh.fb.tile[r][c4 * 4 + 3] * sh.fb.scl[c4 * 4 + 3];
        Of[(size_t)(row0 + r) * (DIM / 4) + g * (GROUP / 4) + c4] = v;
    }
}

// ---------------------------------------------------------------------------
// round-4 direct kernel, retained verbatim as the no/small-workspace fallback
// ---------------------------------------------------------------------------
__global__ __launch_bounds__(256) void rotate_direct(
    const void* __restrict__ Xv,
    const int*  __restrict__ pairs,
    const void* __restrict__ thetav,
    const void* __restrict__ scalesv,
    void* __restrict__ Outv,
    const int* __restrict__ flagp, int defflag)
{
    __shared__ float tile[64][TPAD];
    __shared__ float scl[GROUP];
    const int g    = blockIdx.x;
    const int row0 = blockIdx.y * 64;
    const int tid  = threadIdx.x;
    const int dt   = flagp ? *flagp : defflag;
    const int l    = tid & 63;
    const int w    = tid >> 6;
    const int pmine = w * 16 + (l & 15);

    if (tid < GROUP) {
        int c = g * GROUP + tid;
        scl[tid] = (dt == 1) ? bf16_to_f(((const ushort*)scalesv)[c])
                 : (dt == 2) ? fp16_to_f(((const ushort*)scalesv)[c])
                 : ((const float*)scalesv)[c];
    }
    int A[KROT], B[KROT]; float C[KROT], S[KROT];
    #pragma unroll
    for (int k = 0; k < KROT; ++k) {
        A[k] = pairs[k * DIM + g * GROUP + 2 * pmine];
        B[k] = pairs[k * DIM + g * GROUP + 2 * pmine + 1];
        int ti = k * (DIM / 2) + g * (GROUP / 2) + pmine;
        float th = (dt == 1) ? bf16_to_f(((const ushort*)thetav)[ti])
                 : (dt == 2) ? fp16_to_f(((const ushort*)thetav)[ti])
                 : ((const float*)thetav)[ti];
        C[k] = __builtin_cosf(th);
        S[k] = __builtin_sinf(th);
    }
    if (dt == 0) {
        const float4* X4 = (const float4*)Xv;
        for (int i = tid; i < 64 * 32; i += 256) {
            int r = i >> 5, c4 = i & 31;
            float4 v = X4[(size_t)(row0 + r) * (DIM / 4) + g * (GROUP / 4) + c4];
            tile[r][c4 * 4 + 0] = v.x; tile[r][c4 * 4 + 1] = v.y;
            tile[r][c4 * 4 + 2] = v.z; tile[r][c4 * 4 + 3] = v.w;
        }
    } else {
        const uint4* X4 = (const uint4*)Xv;
        for (int i = tid; i < 64 * 16; i += 256) {
            int r = i >> 4, c8 = i & 15;
            uint4 wv = X4[(size_t)(row0 + r) * (DIM / 8) + g * (GROUP / 8) + c8];
            uint32 ws[4] = { wv.x, wv.y, wv.z, wv.w };
            #pragma unroll
            for (int h2 = 0; h2 < 4; ++h2) {
                ushort lo = (ushort)(ws[h2] & 0xffffu);
                ushort hi = (ushort)(ws[h2] >> 16);
                tile[r][c8 * 8 + 2 * h2]     = (dt == 1) ? bf16_to_f(lo) : fp16_to_f(lo);
                tile[r][c8 * 8 + 2 * h2 + 1] = (dt == 1) ? bf16_to_f(hi) : fp16_to_f(hi);
            }
        }
    }
    __syncthreads();
    #pragma unroll
    for (int k = 0; k < KROT; ++k) {
        #pragma unroll
        for (int pp = 0; pp < 16; ++pp) {
            int   a = __builtin_amdgcn_readlane(A[k], pp);
            int   b = __builtin_amdgcn_readlane(B[k], pp);
            float c = bcast_f(C[k], pp);
            float s = bcast_f(S[k], pp);
            float xa = tile[l][a], xb = tile[l][b];
            tile[l][a] = c * xa - s * xb;
            tile[l][b] = s * xa + c * xb;
        }
        __syncthreads();
    }
    if (dt == 0) {
        float4* O4 = (float4*)Outv;
        for (int i = tid; i < 64 * 32; i += 256) {
            int r = i >> 5, c4 = i & 31;
            float4 v;
            v.x = tile[r][c4 * 4 + 0] * scl[c4 * 4 + 0];
            v.y = tile[r][c4 * 4 + 1] * scl[c4 * 4 + 1];
            v.z = tile[r][c4 * 4 + 2] * scl[c4 * 4 + 2];
            v.w = tile[r][c4 * 4 + 3] * scl[c4 * 4 + 3];
            O4[(size_t)(row0 + r) * (DIM / 4) + g * (GROUP / 4) + c4] = v;
        }
    } else {
        uint4* O4 = (uint4*)Outv;
        for (int i = tid; i < 64 * 16; i += 256) {
            int r = i >> 4, c8 = i & 15;
            uint32 ws[4];
            #pragma unroll
            for (int h2 = 0; h2 < 4; ++h2) {
                float lo = tile[r][c8 * 8 + 2 * h2]     * scl[c8 * 8 + 2 * h2];
                float hi = tile[r][c8 * 8 + 2 * h2 + 1] * scl[c8 * 8 + 2 * h2 + 1];
                ushort ulo = (dt == 1) ? f_to_bf16(lo) : f_to_fp16(lo);
                ushort uhi = (dt == 1) ? f_to_bf16(hi) : f_to_fp16(hi);
                ws[h2] = (uint32)ulo | ((uint32)uhi << 16);
            }
            uint4 wv; wv.x = ws[0]; wv.y = ws[1]; wv.z = ws[2]; wv.w = ws[3];
            O4[(size_t)(row0 + r) * (DIM / 8) + g * (GROUP / 8) + c8] = wv;
        }
    }
}

extern "C" void kernel_launch(void* const* d_in, const int* in_sizes, int n_in,
                              void* d_out, int out_size, void* d_ws, size_t ws_size,
                              hipStream_t stream) {
    const void* x      = d_in[0];
    const int*  pairs  = (const int*)d_in[1];
    const void* theta  = d_in[2];
    const void* scales = d_in[3];

    const int N16 = in_sizes[0] / DIM;     // 16384 rows (16-bit element count)
    const int nrowtiles = N16 / 64;        // 256

    const size_t NEED = 64 + (size_t)NGROUP * GROUP * GROUP * 2;  // flag + Mt (1 MiB)

    if (d_ws != nullptr && ws_size >= NEED) {
        int*    flag = (int*)d_ws;
        ushort* Mt   = (ushort*)((char*)d_ws + 64);
        detect_dtype<<<1, 256, 0, stream>>>((const uint32*)scales, flag);
        compose_M<<<64, 256, 0, stream>>>(pairs, theta, scales, Mt, flag);
        rotate_gemm<<<dim3(nrowtiles, NGROUP), 256, 0, stream>>>(
            x, Mt, d_out, flag, pairs, theta, scales);
    } else if (d_ws != nullptr && ws_size >= sizeof(int)) {
        int* flag = (int*)d_ws;
        detect_dtype<<<1, 256, 0, stream>>>((const uint32*)scales, flag);
        rotate_direct<<<dim3(NGROUP, nrowtiles), 256, 0, stream>>>(
            x, pairs, theta, scales, d_out, flag, 0);
    } else {
        rotate_direct<<<dim3(NGROUP, nrowtiles), 256, 0, stream>>>(
            x, pairs, theta, scales, d_out, nullptr, 0);
    }
}

// Round 4
// 472.688 us; speedup vs baseline: 1.1111x; 1.1111x over previous
//
#include <hip/hip_runtime.h>
#include <hip/hip_fp16.h>

// Rotation_9242769622431 — round 7: resubmit of round 6 (bench infra failed;
// static re-audit found no OOB / divergent-barrier / graph-capture fault).
//
// Design (round-6 theory, unmeasured): harness upcasts everything to fp32
// (round-5 forensics: WRITE=256MiB exact fp32 out, MfmaUtil=0 fallback ran).
// CDNA4 has no fp32 MFMA, but X=Xh+Xl, M=Mh+Ml (fp16 pairs, 22-bit mantissa)
// gives Out = Xh*Mh + Xl*Mh + Xh*Ml fp32-exact (dropped term ~2^-24).
// compose_M: verified rotation loop on identity slab -> transposed fp16 h/l M
// (2 MiB ws, L2-resident). rotate_gemm: 256 persistent blocks (1/CU), zero
// LDS / zero barriers on hot path: M frags live in registers for the whole
// block, X global->reg double-buffered, in-reg split, 3x MFMA per frag,
// nontemporal fp32 stores. Memory floor 512MiB / 6.3TB/s ~ 81us.

typedef unsigned int uint32;
typedef unsigned short ushort;

#define DIM    4096
#define GROUP  128
#define KROT   8
#define NGROUP 32
#define TPAD   (GROUP + 1)

typedef float    f32x4 __attribute__((ext_vector_type(4)));
typedef _Float16 f16x8 __attribute__((ext_vector_type(8)));

union Uh { uint4 u; f16x8 h; };

__device__ __forceinline__ float bf16_to_f(ushort u) {
    union { uint32 i; float f; } v; v.i = ((uint32)u) << 16; return v.f;
}
__device__ __forceinline__ ushort f_to_bf16(float f) {
    union { float f; uint32 i; } v; v.f = f;
    uint32 x = v.i;
    return (ushort)((x + 0x7fffu + ((x >> 16) & 1u)) >> 16);  // RNE
}
__device__ __forceinline__ float fp16_to_f(ushort u) {
    __half h = __ushort_as_half(u); return __half2float(h);
}
__device__ __forceinline__ ushort f_to_fp16(float f) {
    return __half_as_ushort(__float2half_rn(f));
}
__device__ __forceinline__ float bcast_f(float x, int lane) {
    return __uint_as_float(__builtin_amdgcn_readlane(__float_as_uint(x), lane));
}
__device__ __forceinline__ ushort h_bits(_Float16 h) {
    union { _Float16 f; ushort s; } v; v.f = h; return v.s;
}

// flag: 0 = fp32, 1 = bf16, 2 = fp16
__global__ __launch_bounds__(256) void detect_dtype(const uint32* __restrict__ scw,
                                                    int* __restrict__ flag) {
    __shared__ int cbf[256], cfp16[256];
    int b = 0, h = 0;
    for (int i = threadIdx.x; i < 2048; i += 256) {   // 8KB = smallest scales buf
        uint32 lo = scw[i] & 0xffffu;
        b += (lo >= 0x3F00u && lo <= 0x3FC0u);
        h += (lo >= 0x3800u && lo <= 0x3E00u);
    }
    cbf[threadIdx.x] = b; cfp16[threadIdx.x] = h;
    __syncthreads();
    for (int s = 128; s > 0; s >>= 1) {
        if (threadIdx.x < s) { cbf[threadIdx.x] += cbf[threadIdx.x + s];
                               cfp16[threadIdx.x] += cfp16[threadIdx.x + s]; }
        __syncthreads();
    }
    if (threadIdx.x == 0)
        *flag = (cbf[0] > 1024) ? 1 : ((cfp16[0] > 1024) ? 2 : 0);
}

// ---------------------------------------------------------------------------
// compose_M (fp32 path only): 64 blocks = 32 groups x 2 row-halves.
// Applies the verified rotation loop to an identity slab -> M_g = G1..G8*diag(s),
// stores TRANSPOSED fp16 split: Mth[g][j][i], Mtl[g][j][i]  (j=out col, i=in).
// ---------------------------------------------------------------------------
__global__ __launch_bounds__(256) void compose_M(
    const int*  __restrict__ pairs,
    const void* __restrict__ thetav,
    const void* __restrict__ scalesv,
    ushort*     __restrict__ Mth,
    ushort*     __restrict__ Mtl,
    const int*  __restrict__ flagp)
{
    __shared__ float tile[64][TPAD];
    const int dt = *flagp;
    if (dt != 0) return;                       // 16-bit paths don't use M
    const int g    = blockIdx.x >> 1;
    const int half = blockIdx.x & 1;
    const int r0   = half * 64;
    const int tid  = threadIdx.x;
    const int l    = tid & 63;
    const int w    = tid >> 6;
    const int pmine = w * 16 + (l & 15);

    int Ak[KROT], Bk[KROT]; float Ck[KROT], Sk[KROT];
    #pragma unroll
    for (int k = 0; k < KROT; ++k) {
        Ak[k] = pairs[k * DIM + g * GROUP + 2 * pmine];
        Bk[k] = pairs[k * DIM + g * GROUP + 2 * pmine + 1];
        float th = ((const float*)thetav)[k * (DIM / 2) + g * (GROUP / 2) + pmine];
        Ck[k] = __builtin_cosf(th); Sk[k] = __builtin_sinf(th);
    }
    for (int idx = tid; idx < 64 * GROUP; idx += 256) {
        int r = idx >> 7, c = idx & 127;
        tile[r][c] = (r0 + r == c) ? 1.0f : 0.0f;
    }
    __syncthreads();
    #pragma unroll
    for (int k = 0; k < KROT; ++k) {
        #pragma unroll
        for (int pp = 0; pp < 16; ++pp) {
            int   a = __builtin_amdgcn_readlane(Ak[k], pp);
            int   b = __builtin_amdgcn_readlane(Bk[k], pp);
            float c = bcast_f(Ck[k], pp);
            float s = bcast_f(Sk[k], pp);
            float xa = tile[l][a], xb = tile[l][b];
            tile[l][a] = c * xa - s * xb;
            tile[l][b] = s * xa + c * xb;
        }
        __syncthreads();
    }
    // transposed fp16-split store; this block covers i in [r0, r0+64)
    for (int it = 0; it < 4; ++it) {
        int idx = it * 256 + tid;              // 128 j x 8 chunks of 8 i
        int j = idx >> 3, cc = idx & 7;
        float sj = ((const float*)scalesv)[g * GROUP + j];
        union { ushort s[8]; uint4 u; } ph, pl;
        #pragma unroll
        for (int e = 0; e < 8; ++e) {
            float m = tile[cc * 8 + e][j] * sj;
            _Float16 hh = (_Float16)m;
            float r = m - (float)hh;
            ph.s[e] = h_bits(hh);
            pl.s[e] = h_bits((_Float16)r);
        }
        size_t off = (size_t)g * (GROUP * GROUP) + (size_t)j * GROUP + r0 + cc * 8;
        *(uint4*)(Mth + off) = ph.u;
        *(uint4*)(Mtl + off) = pl.u;
    }
}

// ---------------------------------------------------------------------------
// rotate_gemm: 256 persistent blocks (1/CU). g = bid&31 (same-group blocks on
// one XCD), sub = bid>>5 strides row tiles by 8. Wave (wr,wc) 2x2 -> 32x64.
// dt==0: M frags in regs (once), X global->reg dbuf, split, 3xMFMA, NT stores.
// dt!=0: insurance — in-kernel direct rotation (round-4 verified code).
// ---------------------------------------------------------------------------
__global__ __launch_bounds__(256, 1) void rotate_gemm(
    const void* __restrict__ Xv,
    const ushort* __restrict__ Mth,
    const ushort* __restrict__ Mtl,
    void* __restrict__ Outv,
    const int* __restrict__ flagp,
    const int* __restrict__ pairs,
    const void* __restrict__ thetav,
    const void* __restrict__ scalesv,
    int nrows)
{
    __shared__ float tile[64][TPAD];
    __shared__ float scl[GROUP];
    const int dt  = *flagp;
    const int bid = blockIdx.x;
    const int g   = bid & 31;
    const int sub = bid >> 5;
    const int ntiles = nrows >> 6;
    const int tid = threadIdx.x;
    const int l   = tid & 63;
    const int w   = tid >> 6;
    const int lr  = l & 15;
    const int q   = l >> 4;

    if (dt == 0) {
        const int wr = w >> 1, wc = w & 1;
        const float* Xg = (const float*)Xv;
        float*       Og = (float*)Outv;

        // ---- M fragments: loaded once, live in registers all block ----
        uint4 BH[4][4], BL[4][4];
        #pragma unroll
        for (int nf = 0; nf < 4; ++nf) {
            #pragma unroll
            for (int kk = 0; kk < 4; ++kk) {
                size_t off = (size_t)g * (GROUP * GROUP)
                           + (size_t)(wc * 64 + nf * 16 + lr) * GROUP
                           + kk * 32 + q * 8;
                BH[nf][kk] = *(const uint4*)(Mth + off);
                BL[nf][kk] = *(const uint4*)(Mtl + off);
            }
        }

        uint4 A0[2][4][2], A1[2][4][2];

        auto loadA = [&](uint4 (&A)[2][4][2], int t) {
            const int R0 = t * 64;
            #pragma unroll
            for (int mf = 0; mf < 2; ++mf) {
                #pragma unroll
                for (int kk = 0; kk < 4; ++kk) {
                    const float* p = Xg + (size_t)(R0 + wr * 32 + mf * 16 + lr) * DIM
                                        + g * GROUP + kk * 32 + q * 8;
                    A[mf][kk][0] = *(const uint4*)p;
                    A[mf][kk][1] = *(const uint4*)(p + 4);
                }
            }
        };

        auto computeStore = [&](const uint4 (&A)[2][4][2], int t) {
            // split X frags into fp16 h/l
            f16x8 ah[2][4], al[2][4];
            #pragma unroll
            for (int mf = 0; mf < 2; ++mf) {
                #pragma unroll
                for (int kk = 0; kk < 4; ++kk) {
                    f16x8 hv, lv;
                    #pragma unroll
                    for (int h4 = 0; h4 < 2; ++h4) {
                        union { uint4 u; float f[4]; } uu; uu.u = A[mf][kk][h4];
                        #pragma unroll
                        for (int e = 0; e < 4; ++e) {
                            float x = uu.f[e];
                            _Float16 hh = (_Float16)x;
                            float r = x - (float)hh;
                            hv[h4 * 4 + e] = hh;
                            lv[h4 * 4 + e] = (_Float16)r;
                        }
                    }
                    ah[mf][kk] = hv; al[mf][kk] = lv;
                }
            }
            f32x4 acc[2][4];
            #pragma unroll
            for (int mf = 0; mf < 2; ++mf)
                #pragma unroll
                for (int nf = 0; nf < 4; ++nf)
                    acc[mf][nf] = (f32x4)0.0f;
            #pragma unroll
            for (int kk = 0; kk < 4; ++kk) {
                #pragma unroll
                for (int nf = 0; nf < 4; ++nf) {
                    Uh bh, bl; bh.u = BH[nf][kk]; bl.u = BL[nf][kk];
                    #pragma unroll
                    for (int mf = 0; mf < 2; ++mf) {
                        acc[mf][nf] = __builtin_amdgcn_mfma_f32_16x16x32_f16(
                            ah[mf][kk], bh.h, acc[mf][nf], 0, 0, 0);
                        acc[mf][nf] = __builtin_amdgcn_mfma_f32_16x16x32_f16(
                            al[mf][kk], bh.h, acc[mf][nf], 0, 0, 0);
                        acc[mf][nf] = __builtin_amdgcn_mfma_f32_16x16x32_f16(
                            ah[mf][kk], bl.h, acc[mf][nf], 0, 0, 0);
                    }
                }
            }
            // D: col = l&15, row = (l>>4)*4 + j   (m89-verified mapping)
            const int R0 = t * 64;
            #pragma unroll
            for (int mf = 0; mf < 2; ++mf) {
                #pragma unroll
                for (int nf = 0; nf < 4; ++nf) {
                    float* bp = Og + (size_t)(R0 + wr * 32 + mf * 16 + q * 4) * DIM
                                   + g * GROUP + wc * 64 + nf * 16 + lr;
                    #pragma unroll
                    for (int j = 0; j < 4; ++j)
                        __builtin_nontemporal_store(acc[mf][nf][j], bp + (size_t)j * DIM);
                }
            }
        };

        // ---- software-pipelined tile loop (named bufs, static indexing) ----
        int t = sub;
        if (t < ntiles) {
            loadA(A0, t);
            while (true) {
                int t1 = t + 8;
                if (t1 < ntiles) loadA(A1, t1);
                computeStore(A0, t);
                if (t1 >= ntiles) break;
                int t2 = t1 + 8;
                if (t2 < ntiles) loadA(A0, t2);
                computeStore(A1, t1);
                if (t2 >= ntiles) break;
                t = t2;
            }
        }
        return;
    }

    // ------------- dt == 1/2 insurance: direct rotation (round-4) -------------
    {
        const int pmine = w * 16 + (l & 15);
        if (tid < GROUP) {
            int c = g * GROUP + tid;
            scl[tid] = (dt == 1) ? bf16_to_f(((const ushort*)scalesv)[c])
                                 : fp16_to_f(((const ushort*)scalesv)[c]);
        }
        int Ak[KROT], Bk[KROT]; float Ck[KROT], Sk[KROT];
        #pragma unroll
        for (int k = 0; k < KROT; ++k) {
            Ak[k] = pairs[k * DIM + g * GROUP + 2 * pmine];
            Bk[k] = pairs[k * DIM + g * GROUP + 2 * pmine + 1];
            int ti = k * (DIM / 2) + g * (GROUP / 2) + pmine;
            float th = (dt == 1) ? bf16_to_f(((const ushort*)thetav)[ti])
                                 : fp16_to_f(((const ushort*)thetav)[ti]);
            Ck[k] = __builtin_cosf(th); Sk[k] = __builtin_sinf(th);
        }
        for (int t = sub; t < ntiles; t += 8) {
            const int row0 = t * 64;
            const uint4* X4 = (const uint4*)Xv;
            for (int i = tid; i < 64 * 16; i += 256) {
                int r = i >> 4, c8 = i & 15;
                uint4 wv = X4[(size_t)(row0 + r) * (DIM / 8) + g * (GROUP / 8) + c8];
                uint32 ws[4] = { wv.x, wv.y, wv.z, wv.w };
                #pragma unroll
                for (int h2 = 0; h2 < 4; ++h2) {
                    ushort lo = (ushort)(ws[h2] & 0xffffu);
                    ushort hi = (ushort)(ws[h2] >> 16);
                    tile[r][c8 * 8 + 2 * h2]     = (dt == 1) ? bf16_to_f(lo) : fp16_to_f(lo);
                    tile[r][c8 * 8 + 2 * h2 + 1] = (dt == 1) ? bf16_to_f(hi) : fp16_to_f(hi);
                }
            }
            __syncthreads();
            #pragma unroll
            for (int k = 0; k < KROT; ++k) {
                #pragma unroll
                for (int pp = 0; pp < 16; ++pp) {
                    int   a = __builtin_amdgcn_readlane(Ak[k], pp);
                    int   b = __builtin_amdgcn_readlane(Bk[k], pp);
                    float c = bcast_f(Ck[k], pp);
                    float s = bcast_f(Sk[k], pp);
                    float xa = tile[l][a], xb = tile[l][b];
                    tile[l][a] = c * xa - s * xb;
                    tile[l][b] = s * xa + c * xb;
                }
                __syncthreads();
            }
            uint4* O4 = (uint4*)Outv;
            for (int i = tid; i < 64 * 16; i += 256) {
                int r = i >> 4, c8 = i & 15;
                uint32 ws[4];
                #pragma unroll
                for (int h2 = 0; h2 < 4; ++h2) {
                    float lo = tile[r][c8 * 8 + 2 * h2]     * scl[c8 * 8 + 2 * h2];
                    float hi = tile[r][c8 * 8 + 2 * h2 + 1] * scl[c8 * 8 + 2 * h2 + 1];
                    ushort ulo = (dt == 1) ? f_to_bf16(lo) : f_to_fp16(lo);
                    ushort uhi = (dt == 1) ? f_to_bf16(hi) : f_to_fp16(hi);
                    ws[h2] = (uint32)ulo | ((uint32)uhi << 16);
                }
                uint4 wv; wv.x = ws[0]; wv.y = ws[1]; wv.z = ws[2]; wv.w = ws[3];
                O4[(size_t)(row0 + r) * (DIM / 8) + g * (GROUP / 8) + c8] = wv;
            }
            __syncthreads();
        }
    }
}

// ---------------------------------------------------------------------------
// round-4 direct kernel, retained verbatim for the small/no-workspace fallback
// (handles dt 0/1/2; defflag 0 is correct for the real fp32 config)
// ---------------------------------------------------------------------------
__global__ __launch_bounds__(256) void rotate_direct(
    const void* __restrict__ Xv,
    const int*  __restrict__ pairs,
    const void* __restrict__ thetav,
    const void* __restrict__ scalesv,
    void* __restrict__ Outv,
    const int* __restrict__ flagp, int defflag)
{
    __shared__ float tile[64][TPAD];
    __shared__ float scl[GROUP];
    const int g    = blockIdx.x;
    const int row0 = blockIdx.y * 64;
    const int tid  = threadIdx.x;
    const int dt   = flagp ? *flagp : defflag;
    const int l    = tid & 63;
    const int w    = tid >> 6;
    const int pmine = w * 16 + (l & 15);

    if (tid < GROUP) {
        int c = g * GROUP + tid;
        scl[tid] = (dt == 1) ? bf16_to_f(((const ushort*)scalesv)[c])
                 : (dt == 2) ? fp16_to_f(((const ushort*)scalesv)[c])
                 : ((const float*)scalesv)[c];
    }
    int Ak[KROT], Bk[KROT]; float Ck[KROT], Sk[KROT];
    #pragma unroll
    for (int k = 0; k < KROT; ++k) {
        Ak[k] = pairs[k * DIM + g * GROUP + 2 * pmine];
        Bk[k] = pairs[k * DIM + g * GROUP + 2 * pmine + 1];
        int ti = k * (DIM / 2) + g * (GROUP / 2) + pmine;
        float th = (dt == 1) ? bf16_to_f(((const ushort*)thetav)[ti])
                 : (dt == 2) ? fp16_to_f(((const ushort*)thetav)[ti])
                 : ((const float*)thetav)[ti];
        Ck[k] = __builtin_cosf(th);
        Sk[k] = __builtin_sinf(th);
    }
    if (dt == 0) {
        const float4* X4 = (const float4*)Xv;
        for (int i = tid; i < 64 * 32; i += 256) {
            int r = i >> 5, c4 = i & 31;
            float4 v = X4[(size_t)(row0 + r) * (DIM / 4) + g * (GROUP / 4) + c4];
            tile[r][c4 * 4 + 0] = v.x; tile[r][c4 * 4 + 1] = v.y;
            tile[r][c4 * 4 + 2] = v.z; tile[r][c4 * 4 + 3] = v.w;
        }
    } else {
        const uint4* X4 = (const uint4*)Xv;
        for (int i = tid; i < 64 * 16; i += 256) {
            int r = i >> 4, c8 = i & 15;
            uint4 wv = X4[(size_t)(row0 + r) * (DIM / 8) + g * (GROUP / 8) + c8];
            uint32 ws[4] = { wv.x, wv.y, wv.z, wv.w };
            #pragma unroll
            for (int h2 = 0; h2 < 4; ++h2) {
                ushort lo = (ushort)(ws[h2] & 0xffffu);
                ushort hi = (ushort)(ws[h2] >> 16);
                tile[r][c8 * 8 + 2 * h2]     = (dt == 1) ? bf16_to_f(lo) : fp16_to_f(lo);
                tile[r][c8 * 8 + 2 * h2 + 1] = (dt == 1) ? bf16_to_f(hi) : fp16_to_f(hi);
            }
        }
    }
    __syncthreads();
    #pragma unroll
    for (int k = 0; k < KROT; ++k) {
        #pragma unroll
        for (int pp = 0; pp < 16; ++pp) {
            int   a = __builtin_amdgcn_readlane(Ak[k], pp);
            int   b = __builtin_amdgcn_readlane(Bk[k], pp);
            float c = bcast_f(Ck[k], pp);
            float s = bcast_f(Sk[k], pp);
            float xa = tile[l][a], xb = tile[l][b];
            tile[l][a] = c * xa - s * xb;
            tile[l][b] = s * xa + c * xb;
        }
        __syncthreads();
    }
    if (dt == 0) {
        float4* O4 = (float4*)Outv;
        for (int i = tid; i < 64 * 32; i += 256) {
            int r = i >> 5, c4 = i & 31;
            float4 v;
            v.x = tile[r][c4 * 4 + 0] * scl[c4 * 4 + 0];
            v.y = tile[r][c4 * 4 + 1] * scl[c4 * 4 + 1];
            v.z = tile[r][c4 * 4 + 2] * scl[c4 * 4 + 2];
            v.w = tile[r][c4 * 4 + 3] * scl[c4 * 4 + 3];
            O4[(size_t)(row0 + r) * (DIM / 4) + g * (GROUP / 4) + c4] = v;
        }
    } else {
        uint4* O4 = (uint4*)Outv;
        for (int i = tid; i < 64 * 16; i += 256) {
            int r = i >> 4, c8 = i & 15;
            uint32 ws[4];
            #pragma unroll
            for (int h2 = 0; h2 < 4; ++h2) {
                float lo = tile[r][c8 * 8 + 2 * h2]     * scl[c8 * 8 + 2 * h2];
                float hi = tile[r][c8 * 8 + 2 * h2 + 1] * scl[c8 * 8 + 2 * h2 + 1];
                ushort ulo = (dt == 1) ? f_to_bf16(lo) : f_to_fp16(lo);
                ushort uhi = (dt == 1) ? f_to_bf16(hi) : f_to_fp16(hi);
                ws[h2] = (uint32)ulo | ((uint32)uhi << 16);
            }
            uint4 wv; wv.x = ws[0]; wv.y = ws[1]; wv.z = ws[2]; wv.w = ws[3];
            O4[(size_t)(row0 + r) * (DIM / 8) + g * (GROUP / 8) + c8] = wv;
        }
    }
}

extern "C" void kernel_launch(void* const* d_in, const int* in_sizes, int n_in,
                              void* d_out, int out_size, void* d_ws, size_t ws_size,
                              hipStream_t stream) {
    const void* x      = d_in[0];
    const int*  pairs  = (const int*)d_in[1];
    const void* theta  = d_in[2];
    const void* scales = d_in[3];

    const int nrows = in_sizes[0] / DIM;   // element count / DIM = 16384
    const int nrowtiles = nrows / 64;

    const size_t MSZ  = (size_t)NGROUP * GROUP * GROUP * 2;   // 1 MiB per half
    const size_t NEED = 64 + 2 * MSZ;                          // flag + Mth + Mtl

    if (d_ws != nullptr && ws_size >= NEED) {
        int*    flag = (int*)d_ws;
        ushort* Mth  = (ushort*)((char*)d_ws + 64);
        ushort* Mtl  = (ushort*)((char*)d_ws + 64 + MSZ);
        detect_dtype<<<1, 256, 0, stream>>>((const uint32*)scales, flag);
        compose_M<<<64, 256, 0, stream>>>(pairs, theta, scales, Mth, Mtl, flag);
        rotate_gemm<<<256, 256, 0, stream>>>(
            x, Mth, Mtl, d_out, flag, pairs, theta, scales, nrows);
    } else if (d_ws != nullptr && ws_size >= sizeof(int)) {
        int* flag = (int*)d_ws;
        detect_dtype<<<1, 256, 0, stream>>>((const uint32*)scales, flag);
        rotate_direct<<<dim3(NGROUP, nrowtiles), 256, 0, stream>>>(
            x, pairs, theta, scales, d_out, flag, 0);
    } else {
        rotate_direct<<<dim3(NGROUP, nrowtiles), 256, 0, stream>>>(
            x, pairs, theta, scales, d_out, nullptr, 0);
    }
}